// Round 9
// baseline (715.700 us; speedup 1.0000x reference)
//
#include <hip/hip_runtime.h>
#include <hip/hip_bf16.h>
#include <cstdint>

static constexpr int D = 128;       // feature dim (D == H == O == 128)
static constexpr int SPANB = 9;     // bucket span = 512 nodes
static constexpr int CHUNK = 4096;  // edges per binning block

typedef __bf16 v8bf __attribute__((ext_vector_type(8)));
typedef float  v4f  __attribute__((ext_vector_type(4)));

__device__ inline float bflo(unsigned u) { return __uint_as_float(u << 16); }
__device__ inline float bfhi(unsigned u) { return __uint_as_float(u & 0xffff0000u); }
__device__ inline unsigned short bfbits(float f) {
    __hip_bfloat16 h = __float2bfloat16(f);
    return *reinterpret_cast<unsigned short*>(&h);
}
__device__ inline unsigned packbf(float a, float b) {
    return (unsigned)bfbits(a) | ((unsigned)bfbits(b) << 16);
}

// ---------------- mega prep: pack_w (blocks 0-47) + bn_pre+ctr (48-50) + hist (51..50+nblk) + cvt (rest)
__global__ __launch_bounds__(256) void prep_kernel(
    const float* __restrict__ w11, const float* __restrict__ w12,
    const float* __restrict__ w21, const float* __restrict__ w22,
    const float* __restrict__ w31, const float* __restrict__ w32,
    __hip_bfloat16* __restrict__ Wp,
    const float* bn1g, const float* bn1b, const float* bn1m, const float* bn1v, const float* lb1,
    const float* bn2g, const float* bn2b, const float* bn2m, const float* bn2v, const float* lb2,
    const float* bn3g, const float* bn3b, const float* bn3m, const float* bn3v, const float* lb3,
    float* sc1, float* sh1, float* sc2, float* sh2, float* sc3, float* sh3,
    int* __restrict__ wctr,
    const float* __restrict__ x, __hip_bfloat16* __restrict__ xb, long long n8,
    const int* __restrict__ dst, int* __restrict__ blockhist, int nE, int nblk) {
    int b = blockIdx.x, t = threadIdx.x;
    if (b < 48) {
        // weight repack: Wp[w][ks][cf][lane][j] = bf16(W[ks*32+(l>>4)*8+j][cf*16+(l&15)])
        int idx = b * 256 + t;
        int widx = idx >> 11, r = idx & 2047;
        const float* W = widx == 0 ? w11 : widx == 1 ? w12 : widx == 2 ? w21
                       : widx == 3 ? w22 : widx == 4 ? w31 : w32;
        int l = r & 63, cf = (r >> 6) & 7, ks = r >> 9;
        int k0 = ks * 32 + (l >> 4) * 8, c = cf * 16 + (l & 15);
        unsigned o0 = packbf(W[(k0 + 0) * D + c], W[(k0 + 1) * D + c]);
        unsigned o1 = packbf(W[(k0 + 2) * D + c], W[(k0 + 3) * D + c]);
        unsigned o2 = packbf(W[(k0 + 4) * D + c], W[(k0 + 5) * D + c]);
        unsigned o3 = packbf(W[(k0 + 6) * D + c], W[(k0 + 7) * D + c]);
        reinterpret_cast<uint4*>(Wp + (size_t)idx * 8)[0] = make_uint4(o0, o1, o2, o3);
    } else if (b < 51) {
        if (t < D) {
            int j = b - 48;
            const float *g, *bb, *m, *v, *lb;
            float *sc, *sh;
            if (j == 0)      { g = bn1g; bb = bn1b; m = bn1m; v = bn1v; lb = lb1; sc = sc1; sh = sh1; }
            else if (j == 1) { g = bn2g; bb = bn2b; m = bn2m; v = bn2v; lb = lb2; sc = sc2; sh = sh2; }
            else             { g = bn3g; bb = bn3b; m = bn3m; v = bn3v; lb = lb3; sc = sc3; sh = sh3; }
            float s = g[t] * rsqrtf(v[t] + 1e-5f);
            sc[t] = s;
            sh[t] = (lb[t] - m[t]) * s + bb[t];
        }
        if (t == 200) wctr[b - 48] = 0;   // zero the per-layer work counters
    } else if (b < 51 + nblk) {
        __shared__ int h[256];
        h[t] = 0;
        __syncthreads();
        int base = (b - 51) * CHUNK;
#pragma unroll
        for (int i = 0; i < CHUNK / 256; ++i) {
            int e = base + i * 256 + t;
            if (e < nE) atomicAdd(&h[dst[e] >> SPANB], 1);
        }
        __syncthreads();
        blockhist[(b - 51) * 256 + t] = h[t];
    } else {
        long long i = (long long)(b - 51 - nblk) * 256 + t;
        if (i < n8) {
            const float4* f4 = reinterpret_cast<const float4*>(x);
            float4 a = f4[i * 2], bb = f4[i * 2 + 1];
            uint4 o = make_uint4(packbf(a.x, a.y), packbf(a.z, a.w),
                                 packbf(bb.x, bb.y), packbf(bb.z, bb.w));
            reinterpret_cast<uint4*>(xb)[i] = o;
        }
    }
}

// ---------------- CSR build rest ----------------
__global__ __launch_bounds__(256) void bscan_kernel(int* __restrict__ blockhist,
                                                    int* __restrict__ totals, int nblk) {
    __shared__ int s[256];
    int b = blockIdx.x, t = threadIdx.x;
    int running = 0;
    for (int base = 0; base < nblk; base += 256) {
        int idx = base + t;
        int v = (idx < nblk) ? blockhist[idx * 256 + b] : 0;
        s[t] = v;
        __syncthreads();
#pragma unroll
        for (int off = 1; off < 256; off <<= 1) {
            int add = (t >= off) ? s[t - off] : 0;
            __syncthreads();
            s[t] += add;
            __syncthreads();
        }
        if (idx < nblk) blockhist[idx * 256 + b] = running + s[t] - v;
        int tot = s[255];
        __syncthreads();
        running += tot;
    }
    if (t == 0) totals[b] = running;
}

__global__ void tscan_kernel(const int* __restrict__ totals,
                             int* __restrict__ bucketbase, int nbuk, int nE) {
    __shared__ int s[256];
    int t = threadIdx.x;
    int v = (t < nbuk) ? totals[t] : 0;
    s[t] = v;
    __syncthreads();
#pragma unroll
    for (int off = 1; off < 256; off <<= 1) {
        int add = (t >= off) ? s[t - off] : 0;
        __syncthreads();
        s[t] += add;
        __syncthreads();
    }
    if (t < nbuk) bucketbase[t] = s[t] - v;
    if (t == 0) bucketbase[nbuk] = nE;
}

// binning: packed record = (src << SPANB) | (dst & 511)
__global__ __launch_bounds__(256) void fill2_kernel(const int* __restrict__ src,
                                                    const int* __restrict__ dst,
                                                    const int* __restrict__ blockhist,
                                                    const int* __restrict__ bucketbase,
                                                    unsigned* __restrict__ records,
                                                    int nE, int nbuk) {
    __shared__ int cur[256];
    int t = threadIdx.x;
    if (t < nbuk) cur[t] = bucketbase[t] + blockhist[blockIdx.x * 256 + t];
    __syncthreads();
    int base = blockIdx.x * CHUNK;
#pragma unroll
    for (int i = 0; i < CHUNK / 256; ++i) {
        int e = base + i * 256 + t;
        if (e < nE) {
            int d = dst[e], s = src[e];
            int p = atomicAdd(&cur[d >> SPANB], 1);
            records[p] = ((unsigned)s << SPANB) | (unsigned)(d & ((1 << SPANB) - 1));
        }
    }
}

__global__ __launch_bounds__(512) void csr2_kernel(const unsigned* __restrict__ records,
                                                   const int* __restrict__ bucketbase,
                                                   int* __restrict__ rowptr,
                                                   int* __restrict__ col,
                                                   int nN, int nE) {
    __shared__ int cnt[512];
    __shared__ int cur[512];
    int b = blockIdx.x, t = threadIdx.x;
    int node0 = b << SPANB;
    cnt[t] = 0;
    __syncthreads();
    int rbeg = bucketbase[b], rend = bucketbase[b + 1];
    for (int r = rbeg + t; r < rend; r += 512)
        atomicAdd(&cnt[records[r] & ((1 << SPANB) - 1)], 1);
    __syncthreads();
    int v = cnt[t];
#pragma unroll
    for (int off = 1; off < 512; off <<= 1) {
        int add = (t >= off) ? cnt[t - off] : 0;
        __syncthreads();
        cnt[t] += add;
        __syncthreads();
    }
    int pos = rbeg + cnt[t] - v;
    if (node0 + t < nN) rowptr[node0 + t] = pos;
    if (b == 0 && t == 0) rowptr[nN] = nE;
    cur[t] = pos;
    __syncthreads();
    for (int r = rbeg + t; r < rend; r += 512) {
        unsigned rec = records[r];
        int p = atomicAdd(&cur[rec & ((1 << SPANB) - 1)], 1);
        col[p] = (int)(rec >> SPANB);
    }
}

#define ACC8(vv) { a[0]+=bflo(vv.x); a[1]+=bfhi(vv.x); a[2]+=bflo(vv.y); a[3]+=bfhi(vv.y); \
                   a[4]+=bflo(vv.z); a[5]+=bfhi(vv.z); a[6]+=bflo(vv.w); a[7]+=bfhi(vv.w); }

// ---------------- fused layer v3: 4 waves/block, each wave owns a private 8KB LDS
// quadrant and one 32-row tile grabbed from a global work counter. Barrier-free
// (all LDS deps intra-wave); no per-CU block-count remainder (1024 blocks, 4/CU).
// Hout = relu(BN(relu((Hin + gather(Hin))@W1 + b1)@W2))
__global__ __launch_bounds__(256) void layer_kernel(
    const __hip_bfloat16* __restrict__ Hin,
    const int* __restrict__ rowptr, const int* __restrict__ col,
    const __hip_bfloat16* __restrict__ WpA, const __hip_bfloat16* __restrict__ WpB,
    const float* __restrict__ b1,
    const float* __restrict__ sc, const float* __restrict__ sh,
    __hip_bfloat16* __restrict__ Hout, int nN,
    int* __restrict__ wctr, int ntiles) {
    __shared__ __attribute__((aligned(16))) char Sl[4][8192];
    int wv = threadIdx.x >> 6, l = threadIdx.x & 63;
    char* My = Sl[wv];
    const v8bf* Wa = reinterpret_cast<const v8bf*>(WpA);
    const v8bf* Wb = reinterpret_cast<const v8bf*>(WpB);
    const float4* b14 = reinterpret_cast<const float4*>(b1);
    const float4* sc4 = reinterpret_cast<const float4*>(sc);
    const float4* sh4 = reinterpret_cast<const float4*>(sh);
    const uint4* h4 = reinterpret_cast<const uint4*>(Hin);

    for (;;) {
        int t0 = 0;
        if (l == 0) t0 = atomicAdd(wctr, 1);
        int tile = __builtin_amdgcn_readfirstlane(t0);
        if (tile >= ntiles) break;
        int row0 = tile * 32;

        // ---- phase 1: gather (4 groups x 16 lanes, 8 nodes each)
        {
            int grp = l >> 4, q = l & 15;
            for (int n = 0; n < 8; ++n) {
                int r = grp * 8 + n;
                int node = row0 + r;
                int waddr = r * 256 + ((q * 16) ^ ((r & 7) << 4));
                if (node >= nN) {
                    *reinterpret_cast<uint4*>(My + waddr) = make_uint4(0, 0, 0, 0);
                    continue;
                }
                uint4 u = h4[(size_t)node * 16 + q];
                float a[8];
                a[0] = bflo(u.x); a[1] = bfhi(u.x); a[2] = bflo(u.y); a[3] = bfhi(u.y);
                a[4] = bflo(u.z); a[5] = bfhi(u.z); a[6] = bflo(u.w); a[7] = bfhi(u.w);
                int beg = rowptr[node], end = rowptr[node + 1];
                int j = beg;
                for (; j + 3 < end; j += 4) {
                    int s0 = col[j], s1 = col[j + 1], s2 = col[j + 2], s3 = col[j + 3];
                    uint4 v0 = h4[(size_t)s0 * 16 + q];
                    uint4 v1 = h4[(size_t)s1 * 16 + q];
                    uint4 v2 = h4[(size_t)s2 * 16 + q];
                    uint4 v3 = h4[(size_t)s3 * 16 + q];
                    ACC8(v0); ACC8(v1); ACC8(v2); ACC8(v3);
                }
                for (; j < end; ++j) {
                    uint4 v0 = h4[(size_t)col[j] * 16 + q];
                    ACC8(v0);
                }
                *reinterpret_cast<uint4*>(My + waddr) =
                    make_uint4(packbf(a[0], a[1]), packbf(a[2], a[3]),
                               packbf(a[4], a[5]), packbf(a[6], a[7]));
            }
        }
        // no barrier: single wave owns My, DS ops complete in program order

        // ---- phase 2: MLP (two 16-row halves share W fragments)
        int q2 = l >> 4, r16 = l & 15;
        int swz = (r16 & 7) << 4;
        char* srowA = My + r16 * 256;              // rows 0..15
        char* srowB = My + (16 + r16) * 256;       // rows 16..31

        // stage 1
        v4f acc[2][8] = {};
#pragma unroll
        for (int ks = 0; ks < 4; ++ks) {
            v8bf bA = *reinterpret_cast<v8bf*>(srowA + (((ks * 4 + q2) * 16) ^ swz));
            v8bf bB = *reinterpret_cast<v8bf*>(srowB + (((ks * 4 + q2) * 16) ^ swz));
#pragma unroll
            for (int cf = 0; cf < 8; ++cf) {
                v8bf wa = Wa[(ks * 8 + cf) * 64 + l];
                acc[0][cf] = __builtin_amdgcn_mfma_f32_16x16x32_bf16(wa, bA, acc[0][cf], 0, 0, 0);
                acc[1][cf] = __builtin_amdgcn_mfma_f32_16x16x32_bf16(wa, bB, acc[1][cf], 0, 0, 0);
            }
        }
        // mid = relu(acc + b1) -> aliases this wave's rows (reads all done)
#pragma unroll
        for (int half = 0; half < 2; ++half) {
            char* base = My + half * 4096;
#pragma unroll
            for (int cf = 0; cf < 8; ++cf) {
                float4 bb = b14[cf * 4 + q2];
                float e0 = fmaxf(acc[half][cf][0] + bb.x, 0.f);
                float e1 = fmaxf(acc[half][cf][1] + bb.y, 0.f);
                float e2 = fmaxf(acc[half][cf][2] + bb.z, 0.f);
                float e3 = fmaxf(acc[half][cf][3] + bb.w, 0.f);
                int waddr = r16 * 256 + ((cf * 32 + q2 * 8) ^ swz);
                *reinterpret_cast<uint2*>(base + waddr) = make_uint2(packbf(e0, e1), packbf(e2, e3));
            }
        }

        // stage 2
        v4f acc2[2][8] = {};
#pragma unroll
        for (int ks = 0; ks < 4; ++ks) {
            v8bf bA = *reinterpret_cast<v8bf*>(My + r16 * 256 + ((ks * 64 + q2 * 16) ^ swz));
            v8bf bB = *reinterpret_cast<v8bf*>(My + 4096 + r16 * 256 + ((ks * 64 + q2 * 16) ^ swz));
#pragma unroll
            for (int cf = 0; cf < 8; ++cf) {
                v8bf wb = Wb[(ks * 8 + cf) * 64 + l];
                acc2[0][cf] = __builtin_amdgcn_mfma_f32_16x16x32_bf16(wb, bA, acc2[0][cf], 0, 0, 0);
                acc2[1][cf] = __builtin_amdgcn_mfma_f32_16x16x32_bf16(wb, bB, acc2[1][cf], 0, 0, 0);
            }
        }
        // epilogue -> LDS (same swizzled row layout; mid dead after stage-2 reads)
#pragma unroll
        for (int half = 0; half < 2; ++half) {
            char* base = My + half * 4096;
#pragma unroll
            for (int cf = 0; cf < 8; ++cf) {
                float4 s0 = sc4[cf * 4 + q2], s1 = sh4[cf * 4 + q2];
                float e0 = fmaxf(acc2[half][cf][0] * s0.x + s1.x, 0.f);
                float e1 = fmaxf(acc2[half][cf][1] * s0.y + s1.y, 0.f);
                float e2 = fmaxf(acc2[half][cf][2] * s0.z + s1.z, 0.f);
                float e3 = fmaxf(acc2[half][cf][3] * s0.w + s1.w, 0.f);
                int waddr = r16 * 256 + ((cf * 32 + q2 * 8) ^ swz);
                *reinterpret_cast<uint2*>(base + waddr) = make_uint2(packbf(e0, e1), packbf(e2, e3));
            }
        }

        // repack store: contiguous 256B per row (16 lanes x 16B)
        {
            int q = l & 15;
            for (int i = 0; i < 8; ++i) {
                int r = (l >> 4) * 8 + i;
                int grow = row0 + r;
                if (grow < nN) {
                    uint4 v = *reinterpret_cast<uint4*>(My + r * 256 + ((q * 16) ^ ((r & 7) << 4)));
                    reinterpret_cast<uint4*>(Hout + (size_t)grow * D)[q] = v;
                }
            }
        }
    }
}

// ---------------- pooling: one block per graph, binary-search boundaries, LDS reduce
__global__ __launch_bounds__(1024) void pool2_kernel(const __hip_bfloat16* __restrict__ h,
                                                     const int* __restrict__ batch,
                                                     float* __restrict__ out, int nN) {
    int g = blockIdx.x;
    int lo, hi;
    {
        int a = 0, b = nN;
        while (a < b) { int mid = (a + b) >> 1; if (batch[mid] < g) a = mid + 1; else b = mid; }
        lo = a;
        b = nN;
        while (a < b) { int mid = (a + b) >> 1; if (batch[mid] < g + 1) a = mid + 1; else b = mid; }
        hi = a;
    }
    int grp = threadIdx.x >> 4;   // 0..63
    int q = threadIdx.x & 15;
    float a[8] = {};
    const uint4* h4 = reinterpret_cast<const uint4*>(h);
    for (int i = lo + grp; i < hi; i += 64) {
        uint4 v = h4[(size_t)i * 16 + q];
        ACC8(v);
    }
    __shared__ float red[64][130];
#pragma unroll
    for (int k = 0; k < 8; ++k) red[grp][q * 8 + k] = a[k];
    __syncthreads();
    int t = threadIdx.x;
    if (t < D) {
        float s = 0.f;
#pragma unroll 8
        for (int r = 0; r < 64; ++r) s += red[r][t];
        out[(size_t)g * D + t] = s / fmaxf((float)(hi - lo), 1.f);
    }
}

extern "C" void kernel_launch(void* const* d_in, const int* in_sizes, int n_in,
                              void* d_out, int out_size, void* d_ws, size_t ws_size,
                              hipStream_t stream) {
    const float* x    = (const float*)d_in[0];
    const int*   ei   = (const int*)d_in[1];
    const int*   batch= (const int*)d_in[2];
    const float* w11 = (const float*)d_in[3];  const float* b11 = (const float*)d_in[4];
    const float* w12 = (const float*)d_in[5];  const float* b12 = (const float*)d_in[6];
    const float* w21 = (const float*)d_in[7];  const float* b21 = (const float*)d_in[8];
    const float* w22 = (const float*)d_in[9];  const float* b22 = (const float*)d_in[10];
    const float* w31 = (const float*)d_in[11]; const float* b31 = (const float*)d_in[12];
    const float* w32 = (const float*)d_in[13]; const float* b32 = (const float*)d_in[14];
    const float* bn1g = (const float*)d_in[15]; const float* bn1b = (const float*)d_in[16];
    const float* bn1m = (const float*)d_in[17]; const float* bn1v = (const float*)d_in[18];
    const float* bn2g = (const float*)d_in[19]; const float* bn2b = (const float*)d_in[20];
    const float* bn2m = (const float*)d_in[21]; const float* bn2v = (const float*)d_in[22];
    const float* bn3g = (const float*)d_in[23]; const float* bn3b = (const float*)d_in[24];
    const float* bn3m = (const float*)d_in[25]; const float* bn3v = (const float*)d_in[26];

    int nN = in_sizes[0] / D;
    int nE = in_sizes[1] / 2;
    int nG = out_size / D;

    const int* srcp = ei;
    const int* dstp = ei + nE;

    size_t NB2 = (size_t)nN * D * sizeof(__hip_bfloat16);   // 25.6 MB
    char* ws = (char*)d_ws;
    __hip_bfloat16* A16 = (__hip_bfloat16*)ws;              // feature ping
    __hip_bfloat16* B16 = (__hip_bfloat16*)(ws + NB2);      // feature pong (+ CSR scratch early)
    __hip_bfloat16* Wp  = (__hip_bfloat16*)(ws + 2 * NB2);
    size_t wp_bytes = 6 * 2048 * 8 * sizeof(__hip_bfloat16);  // 196608
    char* auxp = ws + 2 * NB2 + wp_bytes;
    size_t aux_bytes = 16384;
    float* sc1 = (float*)auxp + 0,   *sh1 = (float*)auxp + 128;
    float* sc2 = (float*)auxp + 256, *sh2 = (float*)auxp + 384;
    float* sc3 = (float*)auxp + 512, *sh3 = (float*)auxp + 640;
    int*   bucketbase = (int*)(auxp + (768 + 64) * 4);
    int*   totals     = bucketbase + 300;
    int*   wctr       = (int*)(auxp + 8192);               // 3 work counters
    int* rowptr = (int*)(auxp + aux_bytes);
    int* col    = rowptr + (nN + 1);

    // CSR-build scratch overlays B16 (dead until layer-1 output)
    unsigned* records = (unsigned*)B16;                       // nE*4 bytes
    int* blockhist    = (int*)((char*)B16 + (size_t)nE * 4);

    int nbuk = (nN + 511) >> SPANB;
    int nblk = (nE + CHUNK - 1) / CHUNK;
    long long n8 = (long long)nN * D / 8;
    int cvtBlocks = (int)((n8 + 255) / 256);

    // ---- mega prep: pack + bn + ctr-zero + hist + cvt(x -> A16)
    prep_kernel<<<51 + nblk + cvtBlocks, 256, 0, stream>>>(
        w11, w12, w21, w22, w31, w32, Wp,
        bn1g, bn1b, bn1m, bn1v, b12,
        bn2g, bn2b, bn2m, bn2v, b22,
        bn3g, bn3b, bn3m, bn3v, b32,
        sc1, sh1, sc2, sh2, sc3, sh3,
        wctr,
        x, A16, n8,
        dstp, blockhist, nE, nblk);

    // ---- CSR build rest
    bscan_kernel<<<nbuk, 256, 0, stream>>>(blockhist, totals, nblk);
    tscan_kernel<<<1, 256, 0, stream>>>(totals, bucketbase, nbuk, nE);
    fill2_kernel<<<nblk, 256, 0, stream>>>(srcp, dstp, blockhist, bucketbase, records, nE, nbuk);
    csr2_kernel<<<nbuk, 512, 0, stream>>>(records, bucketbase, rowptr, col, nN, nE);

    int ntiles = (nN + 31) / 32;
    int layerBlocks = 1024;                                  // 4 per CU, work-stealing
    __hip_bfloat16* Wp1 = Wp + 0 * 16384; __hip_bfloat16* Wp2 = Wp + 1 * 16384;
    __hip_bfloat16* Wp3 = Wp + 2 * 16384; __hip_bfloat16* Wp4 = Wp + 3 * 16384;
    __hip_bfloat16* Wp5 = Wp + 4 * 16384; __hip_bfloat16* Wp6 = Wp + 5 * 16384;

    // ---- 3 fused layers, ping-pong A<->B
    layer_kernel<<<layerBlocks, 256, 0, stream>>>(A16, rowptr, col, Wp1, Wp2, b11, sc1, sh1, B16, nN, wctr + 0, ntiles);
    layer_kernel<<<layerBlocks, 256, 0, stream>>>(B16, rowptr, col, Wp3, Wp4, b21, sc2, sh2, A16, nN, wctr + 1, ntiles);
    layer_kernel<<<layerBlocks, 256, 0, stream>>>(A16, rowptr, col, Wp5, Wp6, b31, sc3, sh3, B16, nN, wctr + 2, ntiles);

    // ---- global mean pool: one block per graph
    pool2_kernel<<<nG, 1024, 0, stream>>>(B16, batch, (float*)d_out, nN);
}

// Round 12
// 303.496 us; speedup vs baseline: 2.3582x; 2.3582x over previous
//
#include <hip/hip_runtime.h>
#include <hip/hip_bf16.h>
#include <cstdint>

static constexpr int D = 128;       // feature dim (D == H == O == 128)
static constexpr int SPANB = 9;     // bucket span = 512 nodes
static constexpr int CHUNK = 4096;  // edges per binning block

typedef __bf16 v8bf __attribute__((ext_vector_type(8)));
typedef float  v4f  __attribute__((ext_vector_type(4)));

__device__ inline float bflo(unsigned u) { return __uint_as_float(u << 16); }
__device__ inline float bfhi(unsigned u) { return __uint_as_float(u & 0xffff0000u); }
__device__ inline unsigned short bfbits(float f) {
    __hip_bfloat16 h = __float2bfloat16(f);
    return *reinterpret_cast<unsigned short*>(&h);
}
__device__ inline unsigned packbf(float a, float b) {
    return (unsigned)bfbits(a) | ((unsigned)bfbits(b) << 16);
}

// ---------------- mega prep: pack_w (blocks 0-47) + bn_pre (48-50) + hist (51..50+nblk) + cvt (rest)
__global__ __launch_bounds__(256) void prep_kernel(
    const float* __restrict__ w11, const float* __restrict__ w12,
    const float* __restrict__ w21, const float* __restrict__ w22,
    const float* __restrict__ w31, const float* __restrict__ w32,
    __hip_bfloat16* __restrict__ Wp,
    const float* bn1g, const float* bn1b, const float* bn1m, const float* bn1v, const float* lb1,
    const float* bn2g, const float* bn2b, const float* bn2m, const float* bn2v, const float* lb2,
    const float* bn3g, const float* bn3b, const float* bn3m, const float* bn3v, const float* lb3,
    float* sc1, float* sh1, float* sc2, float* sh2, float* sc3, float* sh3,
    const float* __restrict__ x, __hip_bfloat16* __restrict__ xb, long long n8,
    const int* __restrict__ dst, int* __restrict__ blockhist, int nE, int nblk) {
    int b = blockIdx.x, t = threadIdx.x;
    if (b < 48) {
        // weight repack: Wp[w][ks][cf][lane][j] = bf16(W[ks*32+(l>>4)*8+j][cf*16+(l&15)])
        int idx = b * 256 + t;
        int widx = idx >> 11, r = idx & 2047;
        const float* W = widx == 0 ? w11 : widx == 1 ? w12 : widx == 2 ? w21
                       : widx == 3 ? w22 : widx == 4 ? w31 : w32;
        int l = r & 63, cf = (r >> 6) & 7, ks = r >> 9;
        int k0 = ks * 32 + (l >> 4) * 8, c = cf * 16 + (l & 15);
        unsigned o0 = packbf(W[(k0 + 0) * D + c], W[(k0 + 1) * D + c]);
        unsigned o1 = packbf(W[(k0 + 2) * D + c], W[(k0 + 3) * D + c]);
        unsigned o2 = packbf(W[(k0 + 4) * D + c], W[(k0 + 5) * D + c]);
        unsigned o3 = packbf(W[(k0 + 6) * D + c], W[(k0 + 7) * D + c]);
        reinterpret_cast<uint4*>(Wp + (size_t)idx * 8)[0] = make_uint4(o0, o1, o2, o3);
    } else if (b < 51) {
        if (t < D) {
            int j = b - 48;
            const float *g, *bb, *m, *v, *lb;
            float *sc, *sh;
            if (j == 0)      { g = bn1g; bb = bn1b; m = bn1m; v = bn1v; lb = lb1; sc = sc1; sh = sh1; }
            else if (j == 1) { g = bn2g; bb = bn2b; m = bn2m; v = bn2v; lb = lb2; sc = sc2; sh = sh2; }
            else             { g = bn3g; bb = bn3b; m = bn3m; v = bn3v; lb = lb3; sc = sc3; sh = sh3; }
            float s = g[t] * rsqrtf(v[t] + 1e-5f);
            sc[t] = s;
            sh[t] = (lb[t] - m[t]) * s + bb[t];
        }
    } else if (b < 51 + nblk) {
        __shared__ int h[256];
        h[t] = 0;
        __syncthreads();
        int base = (b - 51) * CHUNK;
#pragma unroll
        for (int i = 0; i < CHUNK / 256; ++i) {
            int e = base + i * 256 + t;
            if (e < nE) atomicAdd(&h[dst[e] >> SPANB], 1);
        }
        __syncthreads();
        blockhist[(b - 51) * 256 + t] = h[t];
    } else {
        long long i = (long long)(b - 51 - nblk) * 256 + t;
        if (i < n8) {
            const float4* f4 = reinterpret_cast<const float4*>(x);
            float4 a = f4[i * 2], bb = f4[i * 2 + 1];
            uint4 o = make_uint4(packbf(a.x, a.y), packbf(a.z, a.w),
                                 packbf(bb.x, bb.y), packbf(bb.z, bb.w));
            reinterpret_cast<uint4*>(xb)[i] = o;
        }
    }
}

// ---------------- CSR build rest ----------------
__global__ __launch_bounds__(256) void bscan_kernel(int* __restrict__ blockhist,
                                                    int* __restrict__ totals, int nblk) {
    __shared__ int s[256];
    int b = blockIdx.x, t = threadIdx.x;
    int running = 0;
    for (int base = 0; base < nblk; base += 256) {
        int idx = base + t;
        int v = (idx < nblk) ? blockhist[idx * 256 + b] : 0;
        s[t] = v;
        __syncthreads();
#pragma unroll
        for (int off = 1; off < 256; off <<= 1) {
            int add = (t >= off) ? s[t - off] : 0;
            __syncthreads();
            s[t] += add;
            __syncthreads();
        }
        if (idx < nblk) blockhist[idx * 256 + b] = running + s[t] - v;
        int tot = s[255];
        __syncthreads();
        running += tot;
    }
    if (t == 0) totals[b] = running;
}

__global__ void tscan_kernel(const int* __restrict__ totals,
                             int* __restrict__ bucketbase, int nbuk, int nE) {
    __shared__ int s[256];
    int t = threadIdx.x;
    int v = (t < nbuk) ? totals[t] : 0;
    s[t] = v;
    __syncthreads();
#pragma unroll
    for (int off = 1; off < 256; off <<= 1) {
        int add = (t >= off) ? s[t - off] : 0;
        __syncthreads();
        s[t] += add;
        __syncthreads();
    }
    if (t < nbuk) bucketbase[t] = s[t] - v;
    if (t == 0) bucketbase[nbuk] = nE;
}

// binning: packed record = (src << SPANB) | (dst & 511)
__global__ __launch_bounds__(256) void fill2_kernel(const int* __restrict__ src,
                                                    const int* __restrict__ dst,
                                                    const int* __restrict__ blockhist,
                                                    const int* __restrict__ bucketbase,
                                                    unsigned* __restrict__ records,
                                                    int nE, int nbuk) {
    __shared__ int cur[256];
    int t = threadIdx.x;
    if (t < nbuk) cur[t] = bucketbase[t] + blockhist[blockIdx.x * 256 + t];
    __syncthreads();
    int base = blockIdx.x * CHUNK;
#pragma unroll
    for (int i = 0; i < CHUNK / 256; ++i) {
        int e = base + i * 256 + t;
        if (e < nE) {
            int d = dst[e], s = src[e];
            int p = atomicAdd(&cur[d >> SPANB], 1);
            records[p] = ((unsigned)s << SPANB) | (unsigned)(d & ((1 << SPANB) - 1));
        }
    }
}

__global__ __launch_bounds__(512) void csr2_kernel(const unsigned* __restrict__ records,
                                                   const int* __restrict__ bucketbase,
                                                   int* __restrict__ rowptr,
                                                   int* __restrict__ col,
                                                   int nN, int nE) {
    __shared__ int cnt[512];
    __shared__ int cur[512];
    int b = blockIdx.x, t = threadIdx.x;
    int node0 = b << SPANB;
    cnt[t] = 0;
    __syncthreads();
    int rbeg = bucketbase[b], rend = bucketbase[b + 1];
    for (int r = rbeg + t; r < rend; r += 512)
        atomicAdd(&cnt[records[r] & ((1 << SPANB) - 1)], 1);
    __syncthreads();
    int v = cnt[t];
#pragma unroll
    for (int off = 1; off < 512; off <<= 1) {
        int add = (t >= off) ? cnt[t - off] : 0;
        __syncthreads();
        cnt[t] += add;
        __syncthreads();
    }
    int pos = rbeg + cnt[t] - v;
    if (node0 + t < nN) rowptr[node0 + t] = pos;
    if (b == 0 && t == 0) rowptr[nN] = nE;
    cur[t] = pos;
    __syncthreads();
    for (int r = rbeg + t; r < rend; r += 512) {
        unsigned rec = records[r];
        int p = atomicAdd(&cur[rec & ((1 << SPANB) - 1)], 1);
        col[p] = (int)(rec >> SPANB);
    }
}

#define ACC8(vv) { a[0]+=bflo(vv.x); a[1]+=bfhi(vv.x); a[2]+=bflo(vv.y); a[3]+=bfhi(vv.y); \
                   a[4]+=bflo(vv.z); a[5]+=bfhi(vv.z); a[6]+=bflo(vv.w); a[7]+=bfhi(vv.w); }

// ---------------- gather aggregation (bf16): S[i] = h[i] + sum_{j in nbrs(i)} h[j]
// 16 lanes per node (16B each), 16 nodes per block, unroll 4. (R6's 60us / 3.6TB/s form.)
__global__ __launch_bounds__(256) void agg_kernel(const __hip_bfloat16* __restrict__ h,
                                                  __hip_bfloat16* __restrict__ S,
                                                  const int* __restrict__ rowptr,
                                                  const int* __restrict__ col, int nN) {
    int node = blockIdx.x * 16 + (threadIdx.x >> 4);
    if (node >= nN) return;
    int q = threadIdx.x & 15;
    const uint4* h4 = reinterpret_cast<const uint4*>(h);
    uint4 u = h4[(size_t)node * 16 + q];
    float a[8];
    a[0] = bflo(u.x); a[1] = bfhi(u.x); a[2] = bflo(u.y); a[3] = bfhi(u.y);
    a[4] = bflo(u.z); a[5] = bfhi(u.z); a[6] = bflo(u.w); a[7] = bfhi(u.w);
    int beg = rowptr[node], end = rowptr[node + 1];
    int j = beg;
    for (; j + 3 < end; j += 4) {
        int s0 = col[j], s1 = col[j + 1], s2 = col[j + 2], s3 = col[j + 3];
        uint4 v0 = h4[(size_t)s0 * 16 + q];
        uint4 v1 = h4[(size_t)s1 * 16 + q];
        uint4 v2 = h4[(size_t)s2 * 16 + q];
        uint4 v3 = h4[(size_t)s3 * 16 + q];
        ACC8(v0); ACC8(v1); ACC8(v2); ACC8(v3);
    }
    for (; j < end; ++j) {
        uint4 v0 = h4[(size_t)col[j] * 16 + q];
        ACC8(v0);
    }
    uint4 o = make_uint4(packbf(a[0], a[1]), packbf(a[2], a[3]),
                         packbf(a[4], a[5]), packbf(a[6], a[7]));
    reinterpret_cast<uint4*>(S)[(size_t)node * 16 + q] = o;
}

// ---------------- MLP v3c: out = relu(BN(relu(S@W1 + b1) @ W2))
// 64 rows/block, 4 waves x 16 rows. Two-phase W staging: W1 (32KB) -> stage1 ->
// restage W2 over the same buffer -> stage2. S fragments prefetched to regs before
// the first barrier. Mid tile in per-wave 4KB LDS (intra-wave, no barrier).
// Epilogue repacked to contiguous 256B-row stores.
__global__ __launch_bounds__(256) void mlp3_kernel(
    const __hip_bfloat16* __restrict__ S,
    const __hip_bfloat16* __restrict__ WpA,
    const __hip_bfloat16* __restrict__ WpB,
    const float* __restrict__ b1,
    const float* __restrict__ sc, const float* __restrict__ sh,
    __hip_bfloat16* __restrict__ out, int nN) {
    __shared__ __attribute__((aligned(16))) char Wl[32768];   // one 128x128 bf16 packed W
    __shared__ __attribute__((aligned(16))) char Ml[4][4096]; // per-wave mid tile
    int t = threadIdx.x;
    int w = t >> 6, l = t & 63;
    int q2 = l >> 4, r16 = l & 15;
    int row0 = blockIdx.x * 64 + w * 16;   // wave's base row
    int row = row0 + r16;
    int ar = row < nN ? row : nN - 1;

    // prefetch this lane's 4 S fragments (HBM latency hides under W staging)
    v8bf bfrag[4];
#pragma unroll
    for (int ks = 0; ks < 4; ++ks)
        bfrag[ks] = *reinterpret_cast<const v8bf*>(S + (size_t)ar * D + ks * 32 + q2 * 8);

    uint4* wl = reinterpret_cast<uint4*>(Wl);
    const uint4* wa4 = reinterpret_cast<const uint4*>(WpA);
    const uint4* wb4 = reinterpret_cast<const uint4*>(WpB);

    // ---- stage W1 (2048 uint4 = 32 KB)
#pragma unroll
    for (int i = 0; i < 8; ++i) wl[i * 256 + t] = wa4[i * 256 + t];
    __syncthreads();

    const v8bf* wv = reinterpret_cast<const v8bf*>(Wl);
    const float4* b14 = reinterpret_cast<const float4*>(b1);
    const float4* sc4 = reinterpret_cast<const float4*>(sc);
    const float4* sh4 = reinterpret_cast<const float4*>(sh);
    char* mid = Ml[w];
    int swz = (r16 & 7) << 4;

    // stage 1
    v4f acc[8] = {};
#pragma unroll
    for (int ks = 0; ks < 4; ++ks) {
#pragma unroll
        for (int cf = 0; cf < 8; ++cf)
            acc[cf] = __builtin_amdgcn_mfma_f32_16x16x32_bf16(
                wv[(ks * 8 + cf) * 64 + l], bfrag[ks], acc[cf], 0, 0, 0);
    }
    // mid = relu(acc + b1) -> per-wave LDS (intra-wave, no barrier needed)
#pragma unroll
    for (int cf = 0; cf < 8; ++cf) {
        float4 bb = b14[cf * 4 + q2];
        float e0 = fmaxf(acc[cf][0] + bb.x, 0.f);
        float e1 = fmaxf(acc[cf][1] + bb.y, 0.f);
        float e2 = fmaxf(acc[cf][2] + bb.z, 0.f);
        float e3 = fmaxf(acc[cf][3] + bb.w, 0.f);
        int waddr = r16 * 256 + ((cf * 32 + q2 * 8) ^ swz);
        *reinterpret_cast<uint2*>(mid + waddr) = make_uint2(packbf(e0, e1), packbf(e2, e3));
    }
    __syncthreads();          // all waves done reading W1

    // ---- stage W2 over the same buffer
#pragma unroll
    for (int i = 0; i < 8; ++i) wl[i * 256 + t] = wb4[i * 256 + t];
    __syncthreads();

    // stage 2
    v4f acc2[8] = {};
#pragma unroll
    for (int ks = 0; ks < 4; ++ks) {
        v8bf mfrag = *reinterpret_cast<v8bf*>(mid + r16 * 256 + ((ks * 64 + q2 * 16) ^ swz));
#pragma unroll
        for (int cf = 0; cf < 8; ++cf)
            acc2[cf] = __builtin_amdgcn_mfma_f32_16x16x32_bf16(
                wv[(ks * 8 + cf) * 64 + l], mfrag, acc2[cf], 0, 0, 0);
    }
    // epilogue -> LDS (mid dead after stage-2 reads; intra-wave)
#pragma unroll
    for (int cf = 0; cf < 8; ++cf) {
        float4 s0 = sc4[cf * 4 + q2], s1 = sh4[cf * 4 + q2];
        float e0 = fmaxf(acc2[cf][0] * s0.x + s1.x, 0.f);
        float e1 = fmaxf(acc2[cf][1] * s0.y + s1.y, 0.f);
        float e2 = fmaxf(acc2[cf][2] * s0.z + s1.z, 0.f);
        float e3 = fmaxf(acc2[cf][3] * s0.w + s1.w, 0.f);
        int waddr = r16 * 256 + ((cf * 32 + q2 * 8) ^ swz);
        *reinterpret_cast<uint2*>(mid + waddr) = make_uint2(packbf(e0, e1), packbf(e2, e3));
    }
    // repack store: contiguous 256B per row (16 lanes x 16B); 4 rows per lane
    {
        int q = l & 15;
#pragma unroll
        for (int i = 0; i < 4; ++i) {
            int r = (l >> 4) * 4 + i;          // local row 0..15 within the wave
            int grow = row0 + r;               // row0 is the wave base (no r16!)
            if (grow < nN) {
                uint4 v = *reinterpret_cast<uint4*>(mid + r * 256 + ((q * 16) ^ ((r & 7) << 4)));
                reinterpret_cast<uint4*>(out + (size_t)grow * D)[q] = v;
            }
        }
    }
}

// ---------------- pooling: one block per graph, binary-search boundaries, LDS reduce
__global__ __launch_bounds__(1024) void pool2_kernel(const __hip_bfloat16* __restrict__ h,
                                                     const int* __restrict__ batch,
                                                     float* __restrict__ out, int nN) {
    int g = blockIdx.x;
    int lo, hi;
    {
        int a = 0, b = nN;
        while (a < b) { int mid = (a + b) >> 1; if (batch[mid] < g) a = mid + 1; else b = mid; }
        lo = a;
        b = nN;
        while (a < b) { int mid = (a + b) >> 1; if (batch[mid] < g + 1) a = mid + 1; else b = mid; }
        hi = a;
    }
    int grp = threadIdx.x >> 4;   // 0..63
    int q = threadIdx.x & 15;
    float a[8] = {};
    const uint4* h4 = reinterpret_cast<const uint4*>(h);
    for (int i = lo + grp; i < hi; i += 64) {
        uint4 v = h4[(size_t)i * 16 + q];
        ACC8(v);
    }
    __shared__ float red[64][130];
#pragma unroll
    for (int k = 0; k < 8; ++k) red[grp][q * 8 + k] = a[k];
    __syncthreads();
    int t = threadIdx.x;
    if (t < D) {
        float s = 0.f;
#pragma unroll 8
        for (int r = 0; r < 64; ++r) s += red[r][t];
        out[(size_t)g * D + t] = s / fmaxf((float)(hi - lo), 1.f);
    }
}

extern "C" void kernel_launch(void* const* d_in, const int* in_sizes, int n_in,
                              void* d_out, int out_size, void* d_ws, size_t ws_size,
                              hipStream_t stream) {
    const float* x    = (const float*)d_in[0];
    const int*   ei   = (const int*)d_in[1];
    const int*   batch= (const int*)d_in[2];
    const float* w11 = (const float*)d_in[3];  const float* b11 = (const float*)d_in[4];
    const float* w12 = (const float*)d_in[5];  const float* b12 = (const float*)d_in[6];
    const float* w21 = (const float*)d_in[7];  const float* b21 = (const float*)d_in[8];
    const float* w22 = (const float*)d_in[9];  const float* b22 = (const float*)d_in[10];
    const float* w31 = (const float*)d_in[11]; const float* b31 = (const float*)d_in[12];
    const float* w32 = (const float*)d_in[13]; const float* b32 = (const float*)d_in[14];
    const float* bn1g = (const float*)d_in[15]; const float* bn1b = (const float*)d_in[16];
    const float* bn1m = (const float*)d_in[17]; const float* bn1v = (const float*)d_in[18];
    const float* bn2g = (const float*)d_in[19]; const float* bn2b = (const float*)d_in[20];
    const float* bn2m = (const float*)d_in[21]; const float* bn2v = (const float*)d_in[22];
    const float* bn3g = (const float*)d_in[23]; const float* bn3b = (const float*)d_in[24];
    const float* bn3m = (const float*)d_in[25]; const float* bn3v = (const float*)d_in[26];

    int nN = in_sizes[0] / D;
    int nE = in_sizes[1] / 2;
    int nG = out_size / D;

    const int* srcp = ei;
    const int* dstp = ei + nE;

    size_t NB2 = (size_t)nN * D * sizeof(__hip_bfloat16);   // 25.6 MB
    char* ws = (char*)d_ws;
    __hip_bfloat16* A16 = (__hip_bfloat16*)ws;              // feature ping
    __hip_bfloat16* B16 = (__hip_bfloat16*)(ws + NB2);      // feature pong
    __hip_bfloat16* S16 = (__hip_bfloat16*)(ws + 2 * NB2);  // aggregated (+ CSR scratch early)
    __hip_bfloat16* Wp  = (__hip_bfloat16*)(ws + 3 * NB2);
    size_t wp_bytes = 6 * 2048 * 8 * sizeof(__hip_bfloat16);  // 196608
    char* auxp = ws + 3 * NB2 + wp_bytes;
    size_t aux_bytes = 16384;
    float* sc1 = (float*)auxp + 0,   *sh1 = (float*)auxp + 128;
    float* sc2 = (float*)auxp + 256, *sh2 = (float*)auxp + 384;
    float* sc3 = (float*)auxp + 512, *sh3 = (float*)auxp + 640;
    int*   bucketbase = (int*)(auxp + (768 + 64) * 4);
    int*   totals     = bucketbase + 300;
    int* rowptr = (int*)(auxp + aux_bytes);
    int* col    = rowptr + (nN + 1);

    // CSR-build scratch overlays S16 (dead until first agg)
    unsigned* records = (unsigned*)S16;                       // nE*4 bytes
    int* blockhist    = (int*)((char*)S16 + (size_t)nE * 4);

    int nbuk = (nN + 511) >> SPANB;
    int nblk = (nE + CHUNK - 1) / CHUNK;
    long long n8 = (long long)nN * D / 8;
    int cvtBlocks = (int)((n8 + 255) / 256);

    // ---- mega prep: pack + bn + hist + cvt(x -> A16)
    prep_kernel<<<51 + nblk + cvtBlocks, 256, 0, stream>>>(
        w11, w12, w21, w22, w31, w32, Wp,
        bn1g, bn1b, bn1m, bn1v, b12,
        bn2g, bn2b, bn2m, bn2v, b22,
        bn3g, bn3b, bn3m, bn3v, b32,
        sc1, sh1, sc2, sh2, sc3, sh3,
        x, A16, n8,
        dstp, blockhist, nE, nblk);

    // ---- CSR build rest
    bscan_kernel<<<nbuk, 256, 0, stream>>>(blockhist, totals, nblk);
    tscan_kernel<<<1, 256, 0, stream>>>(totals, bucketbase, nbuk, nE);
    fill2_kernel<<<nblk, 256, 0, stream>>>(srcp, dstp, blockhist, bucketbase, records, nE, nbuk);
    csr2_kernel<<<nbuk, 512, 0, stream>>>(records, bucketbase, rowptr, col, nN, nE);

    int aggBlocks = (nN + 15) / 16;
    int mlpBlocks = (nN + 63) / 64;
    __hip_bfloat16* Wp1 = Wp + 0 * 16384; __hip_bfloat16* Wp2 = Wp + 1 * 16384;
    __hip_bfloat16* Wp3 = Wp + 2 * 16384; __hip_bfloat16* Wp4 = Wp + 3 * 16384;
    __hip_bfloat16* Wp5 = Wp + 4 * 16384; __hip_bfloat16* Wp6 = Wp + 5 * 16384;

    // ---- layer 1 (x lives in A16 as bf16)
    agg_kernel<<<aggBlocks, 256, 0, stream>>>(A16, S16, rowptr, col, nN);
    mlp3_kernel<<<mlpBlocks, 256, 0, stream>>>(S16, Wp1, Wp2, b11, sc1, sh1, B16, nN);

    // ---- layer 2
    agg_kernel<<<aggBlocks, 256, 0, stream>>>(B16, S16, rowptr, col, nN);
    mlp3_kernel<<<mlpBlocks, 256, 0, stream>>>(S16, Wp3, Wp4, b21, sc2, sh2, A16, nN);

    // ---- layer 3
    agg_kernel<<<aggBlocks, 256, 0, stream>>>(A16, S16, rowptr, col, nN);
    mlp3_kernel<<<mlpBlocks, 256, 0, stream>>>(S16, Wp5, Wp6, b31, sc3, sh3, B16, nN);

    // ---- global mean pool: one block per graph
    pool2_kernel<<<nG, 1024, 0, stream>>>(B16, batch, (float*)d_out, nN);
}

// Round 13
// 289.487 us; speedup vs baseline: 2.4723x; 1.0484x over previous
//
#include <hip/hip_runtime.h>
#include <hip/hip_bf16.h>
#include <cstdint>

static constexpr int D = 128;       // feature dim (D == H == O == 128)
static constexpr int SPANB = 9;     // bucket span = 512 nodes
static constexpr int CHUNK = 4096;  // edges per binning block

typedef __bf16 v8bf __attribute__((ext_vector_type(8)));
typedef float  v4f  __attribute__((ext_vector_type(4)));

__device__ inline float bflo(unsigned u) { return __uint_as_float(u << 16); }
__device__ inline float bfhi(unsigned u) { return __uint_as_float(u & 0xffff0000u); }
__device__ inline unsigned short bfbits(float f) {
    __hip_bfloat16 h = __float2bfloat16(f);
    return *reinterpret_cast<unsigned short*>(&h);
}
__device__ inline unsigned packbf(float a, float b) {
    return (unsigned)bfbits(a) | ((unsigned)bfbits(b) << 16);
}

// ---------------- mega prep: pack_w (blocks 0-47) + bn_pre (48-50) + hist (51..50+nblk) + cvt (rest)
__global__ __launch_bounds__(256) void prep_kernel(
    const float* __restrict__ w11, const float* __restrict__ w12,
    const float* __restrict__ w21, const float* __restrict__ w22,
    const float* __restrict__ w31, const float* __restrict__ w32,
    __hip_bfloat16* __restrict__ Wp,
    const float* bn1g, const float* bn1b, const float* bn1m, const float* bn1v, const float* lb1,
    const float* bn2g, const float* bn2b, const float* bn2m, const float* bn2v, const float* lb2,
    const float* bn3g, const float* bn3b, const float* bn3m, const float* bn3v, const float* lb3,
    float* sc1, float* sh1, float* sc2, float* sh2, float* sc3, float* sh3,
    const float* __restrict__ x, __hip_bfloat16* __restrict__ xb, long long n8,
    const int* __restrict__ dst, int* __restrict__ blockhist, int nE, int nblk) {
    int b = blockIdx.x, t = threadIdx.x;
    if (b < 48) {
        // weight repack: Wp[w][ks][cf][lane][j] = bf16(W[ks*32+(l>>4)*8+j][cf*16+(l&15)])
        int idx = b * 256 + t;
        int widx = idx >> 11, r = idx & 2047;
        const float* W = widx == 0 ? w11 : widx == 1 ? w12 : widx == 2 ? w21
                       : widx == 3 ? w22 : widx == 4 ? w31 : w32;
        int l = r & 63, cf = (r >> 6) & 7, ks = r >> 9;
        int k0 = ks * 32 + (l >> 4) * 8, c = cf * 16 + (l & 15);
        unsigned o0 = packbf(W[(k0 + 0) * D + c], W[(k0 + 1) * D + c]);
        unsigned o1 = packbf(W[(k0 + 2) * D + c], W[(k0 + 3) * D + c]);
        unsigned o2 = packbf(W[(k0 + 4) * D + c], W[(k0 + 5) * D + c]);
        unsigned o3 = packbf(W[(k0 + 6) * D + c], W[(k0 + 7) * D + c]);
        reinterpret_cast<uint4*>(Wp + (size_t)idx * 8)[0] = make_uint4(o0, o1, o2, o3);
    } else if (b < 51) {
        if (t < D) {
            int j = b - 48;
            const float *g, *bb, *m, *v, *lb;
            float *sc, *sh;
            if (j == 0)      { g = bn1g; bb = bn1b; m = bn1m; v = bn1v; lb = lb1; sc = sc1; sh = sh1; }
            else if (j == 1) { g = bn2g; bb = bn2b; m = bn2m; v = bn2v; lb = lb2; sc = sc2; sh = sh2; }
            else             { g = bn3g; bb = bn3b; m = bn3m; v = bn3v; lb = lb3; sc = sc3; sh = sh3; }
            float s = g[t] * rsqrtf(v[t] + 1e-5f);
            sc[t] = s;
            sh[t] = (lb[t] - m[t]) * s + bb[t];
        }
    } else if (b < 51 + nblk) {
        __shared__ int h[256];
        h[t] = 0;
        __syncthreads();
        int base = (b - 51) * CHUNK;
#pragma unroll
        for (int i = 0; i < CHUNK / 256; ++i) {
            int e = base + i * 256 + t;
            if (e < nE) atomicAdd(&h[dst[e] >> SPANB], 1);
        }
        __syncthreads();
        blockhist[(b - 51) * 256 + t] = h[t];
    } else {
        long long i = (long long)(b - 51 - nblk) * 256 + t;
        if (i < n8) {
            const float4* f4 = reinterpret_cast<const float4*>(x);
            float4 a = f4[i * 2], bb = f4[i * 2 + 1];
            uint4 o = make_uint4(packbf(a.x, a.y), packbf(a.z, a.w),
                                 packbf(bb.x, bb.y), packbf(bb.z, bb.w));
            reinterpret_cast<uint4*>(xb)[i] = o;
        }
    }
}

// ---------------- CSR build rest ----------------
__global__ __launch_bounds__(256) void bscan_kernel(int* __restrict__ blockhist,
                                                    int* __restrict__ totals, int nblk) {
    __shared__ int s[256];
    int b = blockIdx.x, t = threadIdx.x;
    int running = 0;
    for (int base = 0; base < nblk; base += 256) {
        int idx = base + t;
        int v = (idx < nblk) ? blockhist[idx * 256 + b] : 0;
        s[t] = v;
        __syncthreads();
#pragma unroll
        for (int off = 1; off < 256; off <<= 1) {
            int add = (t >= off) ? s[t - off] : 0;
            __syncthreads();
            s[t] += add;
            __syncthreads();
        }
        if (idx < nblk) blockhist[idx * 256 + b] = running + s[t] - v;
        int tot = s[255];
        __syncthreads();
        running += tot;
    }
    if (t == 0) totals[b] = running;
}

__global__ void tscan_kernel(const int* __restrict__ totals,
                             int* __restrict__ bucketbase, int nbuk, int nE) {
    __shared__ int s[256];
    int t = threadIdx.x;
    int v = (t < nbuk) ? totals[t] : 0;
    s[t] = v;
    __syncthreads();
#pragma unroll
    for (int off = 1; off < 256; off <<= 1) {
        int add = (t >= off) ? s[t - off] : 0;
        __syncthreads();
        s[t] += add;
        __syncthreads();
    }
    if (t < nbuk) bucketbase[t] = s[t] - v;
    if (t == 0) bucketbase[nbuk] = nE;
}

// binning: packed record = (src << SPANB) | (dst & 511)
__global__ __launch_bounds__(256) void fill2_kernel(const int* __restrict__ src,
                                                    const int* __restrict__ dst,
                                                    const int* __restrict__ blockhist,
                                                    const int* __restrict__ bucketbase,
                                                    unsigned* __restrict__ records,
                                                    int nE, int nbuk) {
    __shared__ int cur[256];
    int t = threadIdx.x;
    if (t < nbuk) cur[t] = bucketbase[t] + blockhist[blockIdx.x * 256 + t];
    __syncthreads();
    int base = blockIdx.x * CHUNK;
#pragma unroll
    for (int i = 0; i < CHUNK / 256; ++i) {
        int e = base + i * 256 + t;
        if (e < nE) {
            int d = dst[e], s = src[e];
            int p = atomicAdd(&cur[d >> SPANB], 1);
            records[p] = ((unsigned)s << SPANB) | (unsigned)(d & ((1 << SPANB) - 1));
        }
    }
}

__global__ __launch_bounds__(512) void csr2_kernel(const unsigned* __restrict__ records,
                                                   const int* __restrict__ bucketbase,
                                                   int* __restrict__ rowptr,
                                                   int* __restrict__ col,
                                                   int nN, int nE) {
    __shared__ int cnt[512];
    __shared__ int cur[512];
    int b = blockIdx.x, t = threadIdx.x;
    int node0 = b << SPANB;
    cnt[t] = 0;
    __syncthreads();
    int rbeg = bucketbase[b], rend = bucketbase[b + 1];
    for (int r = rbeg + t; r < rend; r += 512)
        atomicAdd(&cnt[records[r] & ((1 << SPANB) - 1)], 1);
    __syncthreads();
    int v = cnt[t];
#pragma unroll
    for (int off = 1; off < 512; off <<= 1) {
        int add = (t >= off) ? cnt[t - off] : 0;
        __syncthreads();
        cnt[t] += add;
        __syncthreads();
    }
    int pos = rbeg + cnt[t] - v;
    if (node0 + t < nN) rowptr[node0 + t] = pos;
    if (b == 0 && t == 0) rowptr[nN] = nE;
    cur[t] = pos;
    __syncthreads();
    for (int r = rbeg + t; r < rend; r += 512) {
        unsigned rec = records[r];
        int p = atomicAdd(&cur[rec & ((1 << SPANB) - 1)], 1);
        col[p] = (int)(rec >> SPANB);
    }
}

#define ACC8(vv) { a[0]+=bflo(vv.x); a[1]+=bfhi(vv.x); a[2]+=bflo(vv.y); a[3]+=bfhi(vv.y); \
                   a[4]+=bflo(vv.z); a[5]+=bfhi(vv.z); a[6]+=bflo(vv.w); a[7]+=bfhi(vv.w); }

// ---------------- gather aggregation, XCD-split halves:
// S[i][half] = h[i][half] + sum_{j in nbrs(i)} h[j][half]
// Each 256B row is split into two 128B cache-line halves. Blocks with
// blockIdx%8 in {0..3} do half 0, {4..7} do half 1 -> with round-robin
// block->XCD dispatch, each XCD group only ever touches one line per row,
// halving per-XCD fetch + L2 working set. Correct under ANY mapping.
// 8 lanes per node-half (one 128B line per edge), 32 nodes per block.
__global__ __launch_bounds__(256) void aggh_kernel(const __hip_bfloat16* __restrict__ h,
                                                   __hip_bfloat16* __restrict__ S,
                                                   const int* __restrict__ rowptr,
                                                   const int* __restrict__ col,
                                                   int nN, int nT) {
    int b8 = blockIdx.x & 7;
    int half = b8 >> 2;
    int tile = (blockIdx.x >> 3) * 4 + (b8 & 3);
    if (tile >= nT) return;
    int node = tile * 32 + (threadIdx.x >> 3);
    if (node >= nN) return;
    int off = half * 8 + (threadIdx.x & 7);     // uint4 index within the 16-uint4 row
    const uint4* h4 = reinterpret_cast<const uint4*>(h);
    uint4 u = h4[(size_t)node * 16 + off];
    float a[8];
    a[0] = bflo(u.x); a[1] = bfhi(u.x); a[2] = bflo(u.y); a[3] = bfhi(u.y);
    a[4] = bflo(u.z); a[5] = bfhi(u.z); a[6] = bflo(u.w); a[7] = bfhi(u.w);
    int beg = rowptr[node], end = rowptr[node + 1];
    int j = beg;
    for (; j + 3 < end; j += 4) {
        int s0 = col[j], s1 = col[j + 1], s2 = col[j + 2], s3 = col[j + 3];
        uint4 v0 = h4[(size_t)s0 * 16 + off];
        uint4 v1 = h4[(size_t)s1 * 16 + off];
        uint4 v2 = h4[(size_t)s2 * 16 + off];
        uint4 v3 = h4[(size_t)s3 * 16 + off];
        ACC8(v0); ACC8(v1); ACC8(v2); ACC8(v3);
    }
    for (; j < end; ++j) {
        uint4 v0 = h4[(size_t)col[j] * 16 + off];
        ACC8(v0);
    }
    uint4 o = make_uint4(packbf(a[0], a[1]), packbf(a[2], a[3]),
                         packbf(a[4], a[5]), packbf(a[6], a[7]));
    reinterpret_cast<uint4*>(S)[(size_t)node * 16 + off] = o;
}

// ---------------- MLP v3c: out = relu(BN(relu(S@W1 + b1) @ W2))
// 64 rows/block, 4 waves x 16 rows. Two-phase W staging: W1 (32KB) -> stage1 ->
// restage W2 over the same buffer -> stage2. S fragments prefetched to regs before
// the first barrier. Mid tile in per-wave 4KB LDS (intra-wave, no barrier).
// Epilogue repacked to contiguous 256B-row stores.
__global__ __launch_bounds__(256) void mlp3_kernel(
    const __hip_bfloat16* __restrict__ S,
    const __hip_bfloat16* __restrict__ WpA,
    const __hip_bfloat16* __restrict__ WpB,
    const float* __restrict__ b1,
    const float* __restrict__ sc, const float* __restrict__ sh,
    __hip_bfloat16* __restrict__ out, int nN) {
    __shared__ __attribute__((aligned(16))) char Wl[32768];   // one 128x128 bf16 packed W
    __shared__ __attribute__((aligned(16))) char Ml[4][4096]; // per-wave mid tile
    int t = threadIdx.x;
    int w = t >> 6, l = t & 63;
    int q2 = l >> 4, r16 = l & 15;
    int row0 = blockIdx.x * 64 + w * 16;   // wave's base row
    int row = row0 + r16;
    int ar = row < nN ? row : nN - 1;

    // prefetch this lane's 4 S fragments (HBM latency hides under W staging)
    v8bf bfrag[4];
#pragma unroll
    for (int ks = 0; ks < 4; ++ks)
        bfrag[ks] = *reinterpret_cast<const v8bf*>(S + (size_t)ar * D + ks * 32 + q2 * 8);

    uint4* wl = reinterpret_cast<uint4*>(Wl);
    const uint4* wa4 = reinterpret_cast<const uint4*>(WpA);
    const uint4* wb4 = reinterpret_cast<const uint4*>(WpB);

    // ---- stage W1 (2048 uint4 = 32 KB)
#pragma unroll
    for (int i = 0; i < 8; ++i) wl[i * 256 + t] = wa4[i * 256 + t];
    __syncthreads();

    const v8bf* wv = reinterpret_cast<const v8bf*>(Wl);
    const float4* b14 = reinterpret_cast<const float4*>(b1);
    const float4* sc4 = reinterpret_cast<const float4*>(sc);
    const float4* sh4 = reinterpret_cast<const float4*>(sh);
    char* mid = Ml[w];
    int swz = (r16 & 7) << 4;

    // stage 1
    v4f acc[8] = {};
#pragma unroll
    for (int ks = 0; ks < 4; ++ks) {
#pragma unroll
        for (int cf = 0; cf < 8; ++cf)
            acc[cf] = __builtin_amdgcn_mfma_f32_16x16x32_bf16(
                wv[(ks * 8 + cf) * 64 + l], bfrag[ks], acc[cf], 0, 0, 0);
    }
    // mid = relu(acc + b1) -> per-wave LDS (intra-wave, no barrier needed)
#pragma unroll
    for (int cf = 0; cf < 8; ++cf) {
        float4 bb = b14[cf * 4 + q2];
        float e0 = fmaxf(acc[cf][0] + bb.x, 0.f);
        float e1 = fmaxf(acc[cf][1] + bb.y, 0.f);
        float e2 = fmaxf(acc[cf][2] + bb.z, 0.f);
        float e3 = fmaxf(acc[cf][3] + bb.w, 0.f);
        int waddr = r16 * 256 + ((cf * 32 + q2 * 8) ^ swz);
        *reinterpret_cast<uint2*>(mid + waddr) = make_uint2(packbf(e0, e1), packbf(e2, e3));
    }
    __syncthreads();          // all waves done reading W1

    // ---- stage W2 over the same buffer
#pragma unroll
    for (int i = 0; i < 8; ++i) wl[i * 256 + t] = wb4[i * 256 + t];
    __syncthreads();

    // stage 2
    v4f acc2[8] = {};
#pragma unroll
    for (int ks = 0; ks < 4; ++ks) {
        v8bf mfrag = *reinterpret_cast<v8bf*>(mid + r16 * 256 + ((ks * 64 + q2 * 16) ^ swz));
#pragma unroll
        for (int cf = 0; cf < 8; ++cf)
            acc2[cf] = __builtin_amdgcn_mfma_f32_16x16x32_bf16(
                wv[(ks * 8 + cf) * 64 + l], mfrag, acc2[cf], 0, 0, 0);
    }
    // epilogue -> LDS (mid dead after stage-2 reads; intra-wave)
#pragma unroll
    for (int cf = 0; cf < 8; ++cf) {
        float4 s0 = sc4[cf * 4 + q2], s1 = sh4[cf * 4 + q2];
        float e0 = fmaxf(acc2[cf][0] * s0.x + s1.x, 0.f);
        float e1 = fmaxf(acc2[cf][1] * s0.y + s1.y, 0.f);
        float e2 = fmaxf(acc2[cf][2] * s0.z + s1.z, 0.f);
        float e3 = fmaxf(acc2[cf][3] * s0.w + s1.w, 0.f);
        int waddr = r16 * 256 + ((cf * 32 + q2 * 8) ^ swz);
        *reinterpret_cast<uint2*>(mid + waddr) = make_uint2(packbf(e0, e1), packbf(e2, e3));
    }
    // repack store: contiguous 256B per row (16 lanes x 16B); 4 rows per lane
    {
        int q = l & 15;
#pragma unroll
        for (int i = 0; i < 4; ++i) {
            int r = (l >> 4) * 4 + i;          // local row 0..15 within the wave
            int grow = row0 + r;               // row0 is the wave base
            if (grow < nN) {
                uint4 v = *reinterpret_cast<uint4*>(mid + r * 256 + ((q * 16) ^ ((r & 7) << 4)));
                reinterpret_cast<uint4*>(out + (size_t)grow * D)[q] = v;
            }
        }
    }
}

// ---------------- pooling: one block per graph, binary-search boundaries, LDS reduce
__global__ __launch_bounds__(1024) void pool2_kernel(const __hip_bfloat16* __restrict__ h,
                                                     const int* __restrict__ batch,
                                                     float* __restrict__ out, int nN) {
    int g = blockIdx.x;
    int lo, hi;
    {
        int a = 0, b = nN;
        while (a < b) { int mid = (a + b) >> 1; if (batch[mid] < g) a = mid + 1; else b = mid; }
        lo = a;
        b = nN;
        while (a < b) { int mid = (a + b) >> 1; if (batch[mid] < g + 1) a = mid + 1; else b = mid; }
        hi = a;
    }
    int grp = threadIdx.x >> 4;   // 0..63
    int q = threadIdx.x & 15;
    float a[8] = {};
    const uint4* h4 = reinterpret_cast<const uint4*>(h);
    for (int i = lo + grp; i < hi; i += 64) {
        uint4 v = h4[(size_t)i * 16 + q];
        ACC8(v);
    }
    __shared__ float red[64][130];
#pragma unroll
    for (int k = 0; k < 8; ++k) red[grp][q * 8 + k] = a[k];
    __syncthreads();
    int t = threadIdx.x;
    if (t < D) {
        float s = 0.f;
#pragma unroll 8
        for (int r = 0; r < 64; ++r) s += red[r][t];
        out[(size_t)g * D + t] = s / fmaxf((float)(hi - lo), 1.f);
    }
}

extern "C" void kernel_launch(void* const* d_in, const int* in_sizes, int n_in,
                              void* d_out, int out_size, void* d_ws, size_t ws_size,
                              hipStream_t stream) {
    const float* x    = (const float*)d_in[0];
    const int*   ei   = (const int*)d_in[1];
    const int*   batch= (const int*)d_in[2];
    const float* w11 = (const float*)d_in[3];  const float* b11 = (const float*)d_in[4];
    const float* w12 = (const float*)d_in[5];  const float* b12 = (const float*)d_in[6];
    const float* w21 = (const float*)d_in[7];  const float* b21 = (const float*)d_in[8];
    const float* w22 = (const float*)d_in[9];  const float* b22 = (const float*)d_in[10];
    const float* w31 = (const float*)d_in[11]; const float* b31 = (const float*)d_in[12];
    const float* w32 = (const float*)d_in[13]; const float* b32 = (const float*)d_in[14];
    const float* bn1g = (const float*)d_in[15]; const float* bn1b = (const float*)d_in[16];
    const float* bn1m = (const float*)d_in[17]; const float* bn1v = (const float*)d_in[18];
    const float* bn2g = (const float*)d_in[19]; const float* bn2b = (const float*)d_in[20];
    const float* bn2m = (const float*)d_in[21]; const float* bn2v = (const float*)d_in[22];
    const float* bn3g = (const float*)d_in[23]; const float* bn3b = (const float*)d_in[24];
    const float* bn3m = (const float*)d_in[25]; const float* bn3v = (const float*)d_in[26];

    int nN = in_sizes[0] / D;
    int nE = in_sizes[1] / 2;
    int nG = out_size / D;

    const int* srcp = ei;
    const int* dstp = ei + nE;

    size_t NB2 = (size_t)nN * D * sizeof(__hip_bfloat16);   // 25.6 MB
    char* ws = (char*)d_ws;
    __hip_bfloat16* A16 = (__hip_bfloat16*)ws;              // feature ping
    __hip_bfloat16* B16 = (__hip_bfloat16*)(ws + NB2);      // feature pong
    __hip_bfloat16* S16 = (__hip_bfloat16*)(ws + 2 * NB2);  // aggregated (+ CSR scratch early)
    __hip_bfloat16* Wp  = (__hip_bfloat16*)(ws + 3 * NB2);
    size_t wp_bytes = 6 * 2048 * 8 * sizeof(__hip_bfloat16);  // 196608
    char* auxp = ws + 3 * NB2 + wp_bytes;
    size_t aux_bytes = 16384;
    float* sc1 = (float*)auxp + 0,   *sh1 = (float*)auxp + 128;
    float* sc2 = (float*)auxp + 256, *sh2 = (float*)auxp + 384;
    float* sc3 = (float*)auxp + 512, *sh3 = (float*)auxp + 640;
    int*   bucketbase = (int*)(auxp + (768 + 64) * 4);
    int*   totals     = bucketbase + 300;
    int* rowptr = (int*)(auxp + aux_bytes);
    int* col    = rowptr + (nN + 1);

    // CSR-build scratch overlays S16 (dead until first agg)
    unsigned* records = (unsigned*)S16;                       // nE*4 bytes
    int* blockhist    = (int*)((char*)S16 + (size_t)nE * 4);

    int nbuk = (nN + 511) >> SPANB;
    int nblk = (nE + CHUNK - 1) / CHUNK;
    long long n8 = (long long)nN * D / 8;
    int cvtBlocks = (int)((n8 + 255) / 256);

    // ---- mega prep: pack + bn + hist + cvt(x -> A16)
    prep_kernel<<<51 + nblk + cvtBlocks, 256, 0, stream>>>(
        w11, w12, w21, w22, w31, w32, Wp,
        bn1g, bn1b, bn1m, bn1v, b12,
        bn2g, bn2b, bn2m, bn2v, b22,
        bn3g, bn3b, bn3m, bn3v, b32,
        sc1, sh1, sc2, sh2, sc3, sh3,
        x, A16, n8,
        dstp, blockhist, nE, nblk);

    // ---- CSR build rest
    bscan_kernel<<<nbuk, 256, 0, stream>>>(blockhist, totals, nblk);
    tscan_kernel<<<1, 256, 0, stream>>>(totals, bucketbase, nbuk, nE);
    fill2_kernel<<<nblk, 256, 0, stream>>>(srcp, dstp, blockhist, bucketbase, records, nE, nbuk);
    csr2_kernel<<<nbuk, 512, 0, stream>>>(records, bucketbase, rowptr, col, nN, nE);

    int nT = (nN + 31) / 32;                    // node tiles (32 nodes per block)
    int aggBlocks = ((nT + 3) / 4) * 8;         // 2 halves, XCD-aware %8 layout
    int mlpBlocks = (nN + 63) / 64;
    __hip_bfloat16* Wp1 = Wp + 0 * 16384; __hip_bfloat16* Wp2 = Wp + 1 * 16384;
    __hip_bfloat16* Wp3 = Wp + 2 * 16384; __hip_bfloat16* Wp4 = Wp + 3 * 16384;
    __hip_bfloat16* Wp5 = Wp + 4 * 16384; __hip_bfloat16* Wp6 = Wp + 5 * 16384;

    // ---- layer 1 (x lives in A16 as bf16)
    aggh_kernel<<<aggBlocks, 256, 0, stream>>>(A16, S16, rowptr, col, nN, nT);
    mlp3_kernel<<<mlpBlocks, 256, 0, stream>>>(S16, Wp1, Wp2, b11, sc1, sh1, B16, nN);

    // ---- layer 2
    aggh_kernel<<<aggBlocks, 256, 0, stream>>>(B16, S16, rowptr, col, nN, nT);
    mlp3_kernel<<<mlpBlocks, 256, 0, stream>>>(S16, Wp3, Wp4, b21, sc2, sh2, A16, nN);

    // ---- layer 3
    aggh_kernel<<<aggBlocks, 256, 0, stream>>>(A16, S16, rowptr, col, nN, nT);
    mlp3_kernel<<<mlpBlocks, 256, 0, stream>>>(S16, Wp5, Wp6, b31, sc3, sh3, B16, nN);

    // ---- global mean pool: one block per graph
    pool2_kernel<<<nG, 1024, 0, stream>>>(B16, batch, (float*)d_out, nN);
}